// Round 2
// 5384.640 us; speedup vs baseline: 3.5554x; 3.5554x over previous
//
#include <hip/hip_runtime.h>
#include <math.h>

// Problem constants
#define T_STEPS 2048
#define H 256
#define NBATCH 64
#define OUT_ELEMS 33554432   // NBATCH*T_STEPS*H
#define HSZ 16384            // NBATCH*H

// Chunked pre-activation prefetch for the recurrent kernels
#define CH 4
#define NCHUNK (T_STEPS / CH)

// t-segments for the independent-row MV kernel (layer-1 input transform)
#define TSEG 8
#define TROWS (T_STEPS / TSEG)

// ---------------------------------------------------------------------------
// Phase 1: pre0[b][t][n] = x[b][t][:] @ WI0 + BI0   (written into d_out)
// M=131072 (b*2048+t), N=256, K=256. BM=128, BN=64, BK=16, 256 threads.
// (proven kernel, unchanged from the passing round-0 version)
// ---------------------------------------------------------------------------
__global__ __launch_bounds__(256) void k_gemm_pre0(
    const float* __restrict__ x, const float* __restrict__ WI,
    const float* __restrict__ BI, float* __restrict__ pre)
{
    __shared__ float As[16][132];   // A stored transposed [k][m], padded
    __shared__ float Bs[16][68];
    const int tid = threadIdx.x;
    const size_t mbase = (size_t)blockIdx.x * 128;
    const int nbase = blockIdx.y * 64;
    const int am = tid >> 1, ak = (tid & 1) * 8;
    const int bk = tid >> 4, bn = (tid & 15) * 4;
    const int ty = tid >> 4, tx = tid & 15;
    const int m0 = ty * 8, n0 = tx * 4;
    float acc[8][4];
    #pragma unroll
    for (int i = 0; i < 8; i++)
        #pragma unroll
        for (int j = 0; j < 4; j++) acc[i][j] = 0.f;

    for (int k0 = 0; k0 < 256; k0 += 16) {
        float4 a0 = *(const float4*)(x + (mbase + am) * 256 + k0 + ak);
        float4 a1 = *(const float4*)(x + (mbase + am) * 256 + k0 + ak + 4);
        float4 bv = *(const float4*)(WI + (size_t)(k0 + bk) * 256 + nbase + bn);
        __syncthreads();
        As[ak + 0][am] = a0.x; As[ak + 1][am] = a0.y;
        As[ak + 2][am] = a0.z; As[ak + 3][am] = a0.w;
        As[ak + 4][am] = a1.x; As[ak + 5][am] = a1.y;
        As[ak + 6][am] = a1.z; As[ak + 7][am] = a1.w;
        *(float4*)&Bs[bk][bn] = bv;
        __syncthreads();
        #pragma unroll
        for (int kk = 0; kk < 16; kk++) {
            float4 av0 = *(const float4*)&As[kk][m0];
            float4 av1 = *(const float4*)&As[kk][m0 + 4];
            float4 bv4 = *(const float4*)&Bs[kk][n0];
            float a[8] = {av0.x, av0.y, av0.z, av0.w, av1.x, av1.y, av1.z, av1.w};
            float b[4] = {bv4.x, bv4.y, bv4.z, bv4.w};
            #pragma unroll
            for (int i = 0; i < 8; i++)
                #pragma unroll
                for (int j = 0; j < 4; j++)
                    acc[i][j] += a[i] * b[j];
        }
    }
    float4 bi = *(const float4*)(BI + nbase + n0);
    #pragma unroll
    for (int i = 0; i < 8; i++) {
        float4 r;
        r.x = acc[i][0] + bi.x; r.y = acc[i][1] + bi.y;
        r.z = acc[i][2] + bi.z; r.w = acc[i][3] + bi.w;
        *(float4*)(pre + (mbase + m0 + i) * 256 + nbase + n0) = r;
    }
}

// ---------------------------------------------------------------------------
// Recurrent layer, one workgroup per batch row, fully private recurrence.
//   stream[b][t][j] (in buf, in-place): read pre-activation, write h_t.
//   h state lives in LDS double buffer; W lives in VGPRs (128/thread).
// Thread map: j = tid>>1 (output column), khalf = tid&1 (which 128 k's).
// Association matches the verified round-0 kernel exactly:
//   s00..s03 interleaved partials over a 128-contiguous k-half (float4 walk),
//   acc = (s00+s01)+(s02+s03); acc += partner-half via shfl_xor(1);
//   v = tanhf((acc + pre) + bias).
// No cross-workgroup communication of any kind.
// ---------------------------------------------------------------------------
__global__ __launch_bounds__(512, 2) void k_rec(
    const float* __restrict__ W,      // [256][256] recurrent weights (row k, col j)
    const float* __restrict__ bias_p, // per-column bias (BH row), may differ per layer
    const float* __restrict__ hinit,  // [NBATCH][H] initial hidden state (layer slice)
    float* buf,                       // stream base (aliased read/write; NOT restrict)
    float* hfin)                      // [NBATCH][H] final hidden state out
{
    const int b     = blockIdx.x;
    const int tid   = threadIdx.x;
    const int j     = tid >> 1;
    const int khalf = tid & 1;
    const bool wr   = (khalf == 0);

    __shared__ float hb[2][H];

    // persistent weights: Wr[kk] = W[khalf*128 + kk][j]
    float Wr[128];
    {
        const float* wp = W + (size_t)(khalf * 128) * H + j;
        #pragma unroll
        for (int kk = 0; kk < 128; kk++) Wr[kk] = wp[(size_t)kk * H];
    }
    float bias = 0.f;
    if (wr) bias = bias_p[j];

    if (tid < 64)
        *(float4*)&hb[0][tid * 4] = *(const float4*)(hinit + b * H + tid * 4);

    float* st = buf + (size_t)b * T_STEPS * H;   // this row's [t][j] stream

    float pc[CH], pn[CH];
    if (wr) {
        #pragma unroll
        for (int s = 0; s < CH; s++) pc[s] = st[(size_t)s * H + j];
    }
    __syncthreads();

    for (int n = 0; n < NCHUNK; n++) {
        if (wr && n + 1 < NCHUNK) {            // prefetch next chunk's pre-acts
            #pragma unroll
            for (int s = 0; s < CH; s++)
                pn[s] = st[(size_t)((n + 1) * CH + s) * H + j];
        }
        #pragma unroll
        for (int s = 0; s < CH; s++) {
            const int t = n * CH + s;
            const int par = t & 1;
            const float* hp = &hb[par][khalf * 128];
            float s00 = 0.f, s01 = 0.f, s02 = 0.f, s03 = 0.f;
            #pragma unroll
            for (int q = 0; q < 32; q++) {
                float4 a = *(const float4*)(hp + 4 * q);
                s00 += a.x * Wr[4 * q];     s01 += a.y * Wr[4 * q + 1];
                s02 += a.z * Wr[4 * q + 2]; s03 += a.w * Wr[4 * q + 3];
            }
            float acc = (s00 + s01) + (s02 + s03);
            acc += __shfl_xor(acc, 1, 64);     // combine the two k-halves
            if (wr) {
                float v = tanhf(acc + pc[s] + bias);
                hb[par ^ 1][j] = v;
                st[(size_t)t * H + j] = v;     // in-place: h_t over pre_t
                if (t == T_STEPS - 1) hfin[b * H + j] = v;
            }
            __syncthreads();
        }
        if (wr) { pc[0] = pn[0]; pc[1] = pn[1]; pc[2] = pn[2]; pc[3] = pn[3]; }
    }
}

// ---------------------------------------------------------------------------
// Layer-1 input transform: P[b][t][j] = h0[b][t][:] @ WI1 + BI1, in-place.
// Rows are independent -> parallel over (b, t-segment). Same MV core and
// association as k_rec (bit-matches round-0's role-1 P computation).
// ---------------------------------------------------------------------------
__global__ __launch_bounds__(512, 2) void k_mv1(
    const float* __restrict__ W2,     // WI layer 1
    const float* __restrict__ bias_p, // BI layer 1
    float* buf)
{
    const int b     = blockIdx.x >> 3;       // 64 b  x  TSEG=8 segments
    const int seg   = blockIdx.x & 7;
    const int tid   = threadIdx.x;
    const int j     = tid >> 1;
    const int khalf = tid & 1;
    const bool wr   = (khalf == 0);

    __shared__ float hb[2][H];

    float Wr[128];
    {
        const float* wp = W2 + (size_t)(khalf * 128) * H + j;
        #pragma unroll
        for (int kk = 0; kk < 128; kk++) Wr[kk] = wp[(size_t)kk * H];
    }
    float bias = 0.f;
    if (wr) bias = bias_p[j];

    float* st = buf + (size_t)b * T_STEPS * H;
    const int t0 = seg * TROWS, tend = t0 + TROWS;

    if (tid < 64)
        *(float4*)&hb[0][tid * 4] = *(const float4*)(st + (size_t)t0 * H + tid * 4);
    __syncthreads();

    for (int t = t0; t < tend; t++) {
        const int cur = t & 1;
        float4 nx = make_float4(0.f, 0.f, 0.f, 0.f);
        if (tid < 64 && t + 1 < tend)          // prefetch next row (hides HBM)
            nx = *(const float4*)(st + (size_t)(t + 1) * H + tid * 4);

        const float* hp = &hb[cur][khalf * 128];
        float s00 = 0.f, s01 = 0.f, s02 = 0.f, s03 = 0.f;
        #pragma unroll
        for (int q = 0; q < 32; q++) {
            float4 a = *(const float4*)(hp + 4 * q);
            s00 += a.x * Wr[4 * q];     s01 += a.y * Wr[4 * q + 1];
            s02 += a.z * Wr[4 * q + 2]; s03 += a.w * Wr[4 * q + 3];
        }
        float acc = (s00 + s01) + (s02 + s03);
        acc += __shfl_xor(acc, 1, 64);
        if (wr)
            st[(size_t)t * H + j] = acc + bias;   // in-place: P_t over h0_t
        if (tid < 64 && t + 1 < tend)
            *(float4*)&hb[cur ^ 1][tid * 4] = nx;
        __syncthreads();
    }
}

// ---------------------------------------------------------------------------
extern "C" void kernel_launch(void* const* d_in, const int* in_sizes, int n_in,
                              void* d_out, int out_size, void* d_ws, size_t ws_size,
                              hipStream_t stream)
{
    (void)in_sizes; (void)n_in; (void)out_size; (void)d_ws; (void)ws_size;
    const float* x  = (const float*)d_in[0];
    const float* h0 = (const float*)d_in[1];
    const float* WI = (const float*)d_in[2];
    const float* BI = (const float*)d_in[3];
    const float* WH = (const float*)d_in[4];
    const float* BH = (const float*)d_in[5];
    float* out = (float*)d_out;

    // 1) pre0 = x @ WI0 + BI0                       -> out
    k_gemm_pre0<<<dim3(1024, 4), 256, 0, stream>>>(x, WI, BI, out);
    // 2) layer-0 recurrence, in-place: out <- h0_t stream; h_final[0]
    k_rec<<<64, 512, 0, stream>>>(WH, BH, h0, out, out + OUT_ELEMS);
    // 3) P = h0 @ WI1 + BI1, in-place: out <- P_t stream
    k_mv1<<<NBATCH * TSEG, 512, 0, stream>>>(WI + H * H, BI + H, out);
    // 4) layer-1 recurrence, in-place: out <- h1_t stream (= final output);
    //    h_final[1]
    k_rec<<<64, 512, 0, stream>>>(WH + H * H, BH + H, h0 + HSZ, out,
                                  out + OUT_ELEMS + HSZ);
}

// Round 3
// 4410.623 us; speedup vs baseline: 4.3406x; 1.2208x over previous
//
#include <hip/hip_runtime.h>
#include <math.h>

// Problem constants
#define T_STEPS 2048
#define H 256
#define NBATCH 64
#define OUT_ELEMS 33554432   // NBATCH*T_STEPS*H
#define HSZ 16384            // NBATCH*H

// Chunked pre-activation prefetch for the recurrent kernels
#define CH 4
#define NCHUNK (T_STEPS / CH)

// t-segments for the independent-row MV kernel (layer-1 input transform)
#define TSEG 8
#define TROWS (T_STEPS / TSEG)

// Bank-skewed LDS h row: slice ke (32 floats) starts at 36*ke floats, so the
// 8 slice bases hit banks 0,4,8,...,28 -> each wave ds_read_b128 (8 distinct
// 16B addresses, broadcast within 8-lane groups) covers all 32 banks once.
#define HP 288
#define PD(k) ((k) + (((k) >> 5) << 2))

// 8-lane butterfly reduce on the VALU via DPP (no LDS-pipe traffic).
// Lane groups are tid-aligned to 8, so quad_perm xor1/xor2 + row_half_mirror
// (= xor4 within each 8-lane half-row) leave the group sum in all 8 lanes.
__device__ __forceinline__ float red8(float v) {
    v += __int_as_float(__builtin_amdgcn_update_dpp(
            0, __float_as_int(v), 0xB1, 0xF, 0xF, true));   // quad_perm(1,0,3,2)
    v += __int_as_float(__builtin_amdgcn_update_dpp(
            0, __float_as_int(v), 0x4E, 0xF, 0xF, true));   // quad_perm(2,3,0,1)
    v += __int_as_float(__builtin_amdgcn_update_dpp(
            0, __float_as_int(v), 0x141, 0xF, 0xF, true));  // row_half_mirror
    return v;
}

// ---------------------------------------------------------------------------
// Phase 1: pre0[b][t][n] = x[b][t][:] @ WI0 + BI0   (written into d_out)
// (proven kernel, unchanged)
// ---------------------------------------------------------------------------
__global__ __launch_bounds__(256) void k_gemm_pre0(
    const float* __restrict__ x, const float* __restrict__ WI,
    const float* __restrict__ BI, float* __restrict__ pre)
{
    __shared__ float As[16][132];   // A stored transposed [k][m], padded
    __shared__ float Bs[16][68];
    const int tid = threadIdx.x;
    const size_t mbase = (size_t)blockIdx.x * 128;
    const int nbase = blockIdx.y * 64;
    const int am = tid >> 1, ak = (tid & 1) * 8;
    const int bk = tid >> 4, bn = (tid & 15) * 4;
    const int ty = tid >> 4, tx = tid & 15;
    const int m0 = ty * 8, n0 = tx * 4;
    float acc[8][4];
    #pragma unroll
    for (int i = 0; i < 8; i++)
        #pragma unroll
        for (int j = 0; j < 4; j++) acc[i][j] = 0.f;

    for (int k0 = 0; k0 < 256; k0 += 16) {
        float4 a0 = *(const float4*)(x + (mbase + am) * 256 + k0 + ak);
        float4 a1 = *(const float4*)(x + (mbase + am) * 256 + k0 + ak + 4);
        float4 bv = *(const float4*)(WI + (size_t)(k0 + bk) * 256 + nbase + bn);
        __syncthreads();
        As[ak + 0][am] = a0.x; As[ak + 1][am] = a0.y;
        As[ak + 2][am] = a0.z; As[ak + 3][am] = a0.w;
        As[ak + 4][am] = a1.x; As[ak + 5][am] = a1.y;
        As[ak + 6][am] = a1.z; As[ak + 7][am] = a1.w;
        *(float4*)&Bs[bk][bn] = bv;
        __syncthreads();
        #pragma unroll
        for (int kk = 0; kk < 16; kk++) {
            float4 av0 = *(const float4*)&As[kk][m0];
            float4 av1 = *(const float4*)&As[kk][m0 + 4];
            float4 bv4 = *(const float4*)&Bs[kk][n0];
            float a[8] = {av0.x, av0.y, av0.z, av0.w, av1.x, av1.y, av1.z, av1.w};
            float b[4] = {bv4.x, bv4.y, bv4.z, bv4.w};
            #pragma unroll
            for (int i = 0; i < 8; i++)
                #pragma unroll
                for (int j = 0; j < 4; j++)
                    acc[i][j] += a[i] * b[j];
        }
    }
    float4 bi = *(const float4*)(BI + nbase + n0);
    #pragma unroll
    for (int i = 0; i < 8; i++) {
        float4 r;
        r.x = acc[i][0] + bi.x; r.y = acc[i][1] + bi.y;
        r.z = acc[i][2] + bi.z; r.w = acc[i][3] + bi.w;
        *(float4*)(pre + (mbase + m0 + i) * 256 + nbase + n0) = r;
    }
}

// The register-blocked MV core shared by k_rec / k_mv1.
// Thread map: ke = tid&7 (32-k slice), jb = tid>>3 (4 output columns).
// Wv[kk] = W[ke*32+kk][j0..j0+3] (128 VGPRs persistent).
#define MV_CORE(HROW)                                                       \
    float a0 = 0.f, a1 = 0.f, a2 = 0.f, a3 = 0.f;                           \
    {                                                                       \
        _Pragma("unroll")                                                   \
        for (int q = 0; q < 8; q++) {                                       \
            float4 h4 = *(const float4*)((HROW) + 4 * q);                   \
            float4 w0 = Wv[4*q+0], w1 = Wv[4*q+1];                          \
            float4 w2 = Wv[4*q+2], w3 = Wv[4*q+3];                          \
            a0 += h4.x*w0.x; a0 += h4.y*w1.x; a0 += h4.z*w2.x; a0 += h4.w*w3.x; \
            a1 += h4.x*w0.y; a1 += h4.y*w1.y; a1 += h4.z*w2.y; a1 += h4.w*w3.y; \
            a2 += h4.x*w0.z; a2 += h4.y*w1.z; a2 += h4.z*w2.z; a2 += h4.w*w3.z; \
            a3 += h4.x*w0.w; a3 += h4.y*w1.w; a3 += h4.z*w2.w; a3 += h4.w*w3.w; \
        }                                                                   \
        a0 = red8(a0); a1 = red8(a1); a2 = red8(a2); a3 = red8(a3);         \
    }

// ---------------------------------------------------------------------------
// Recurrent layer: one workgroup per batch row, fully private recurrence.
// h state in skewed LDS double buffer; weights in VGPRs; DPP k-reduce.
// In-place stream: read pre-activation pre_t, write h_t over it.
// ---------------------------------------------------------------------------
__global__ __launch_bounds__(512, 2) void k_rec(
    const float* __restrict__ W,      // [256][256] recurrent weights
    const float* __restrict__ bias_p, // per-column bias row
    const float* __restrict__ hinit,  // [NBATCH][H] initial hidden (layer slice)
    float* buf,                       // stream base (aliased read/write)
    float* hfin)                      // [NBATCH][H] final hidden out
{
    const int b   = blockIdx.x;
    const int tid = threadIdx.x;
    const int ke  = tid & 7;
    const int jb  = tid >> 3;         // 0..63
    const int j0  = jb * 4;
    const int k0  = ke * 32;
    const bool wr = (ke == 0);

    __shared__ float hb[2][HP];

    float4 Wv[32];
    {
        const float* wp = W + (size_t)k0 * H + j0;
        #pragma unroll
        for (int kk = 0; kk < 32; kk++)
            Wv[kk] = *(const float4*)(wp + (size_t)kk * H);
    }
    float4 bias = make_float4(0.f, 0.f, 0.f, 0.f);
    if (wr) bias = *(const float4*)(bias_p + j0);

    if (tid < 64)
        *(float4*)&hb[0][PD(tid * 4)] = *(const float4*)(hinit + b * H + tid * 4);

    float* st = buf + (size_t)b * T_STEPS * H;

    float4 pc[CH], pn[CH];
    if (wr) {
        #pragma unroll
        for (int s = 0; s < CH; s++)
            pc[s] = *(const float4*)(st + (size_t)s * H + j0);
    }
    __syncthreads();

    for (int n = 0; n < NCHUNK; n++) {
        if (wr && n + 1 < NCHUNK) {          // prefetch next chunk's pre-acts
            #pragma unroll
            for (int s = 0; s < CH; s++)
                pn[s] = *(const float4*)(st + (size_t)((n + 1) * CH + s) * H + j0);
        }
        #pragma unroll
        for (int s = 0; s < CH; s++) {
            const int t = n * CH + s;
            const int par = t & 1;
            const float* hrow = &hb[par][36 * ke];   // PD(k0)
            MV_CORE(hrow);
            if (wr) {
                float v0 = tanhf(a0 + pc[s].x + bias.x);
                float v1 = tanhf(a1 + pc[s].y + bias.y);
                float v2 = tanhf(a2 + pc[s].z + bias.z);
                float v3 = tanhf(a3 + pc[s].w + bias.w);
                *(float4*)&hb[par ^ 1][PD(j0)] = make_float4(v0, v1, v2, v3);
                *(float4*)(st + (size_t)t * H + j0) = make_float4(v0, v1, v2, v3);
                if (t == T_STEPS - 1)
                    *(float4*)(hfin + b * H + j0) = make_float4(v0, v1, v2, v3);
            }
            __syncthreads();
        }
        if (wr) { pc[0] = pn[0]; pc[1] = pn[1]; pc[2] = pn[2]; pc[3] = pn[3]; }
    }
}

// ---------------------------------------------------------------------------
// Layer-1 input transform: P[b][t][j] = h0[b][t][:] @ WI1 + BI1, in-place.
// Independent rows -> parallel over (b, t-segment); same MV core.
// ---------------------------------------------------------------------------
__global__ __launch_bounds__(512, 2) void k_mv1(
    const float* __restrict__ W2,     // WI layer 1
    const float* __restrict__ bias_p, // BI layer 1
    float* buf)
{
    const int b   = blockIdx.x >> 3;  // 64 b x TSEG=8 segments
    const int seg = blockIdx.x & 7;
    const int tid = threadIdx.x;
    const int ke  = tid & 7;
    const int jb  = tid >> 3;
    const int j0  = jb * 4;
    const int k0  = ke * 32;
    const bool wr = (ke == 0);

    __shared__ float hb[2][HP];

    float4 Wv[32];
    {
        const float* wp = W2 + (size_t)k0 * H + j0;
        #pragma unroll
        for (int kk = 0; kk < 32; kk++)
            Wv[kk] = *(const float4*)(wp + (size_t)kk * H);
    }
    float4 bias = make_float4(0.f, 0.f, 0.f, 0.f);
    if (wr) bias = *(const float4*)(bias_p + j0);

    float* st = buf + (size_t)b * T_STEPS * H;
    const int t0 = seg * TROWS, tend = t0 + TROWS;

    if (tid < 64)
        *(float4*)&hb[0][PD(tid * 4)] = *(const float4*)(st + (size_t)t0 * H + tid * 4);
    __syncthreads();

    for (int t = t0; t < tend; t++) {
        const int cur = t & 1;
        const bool ld = (tid < 64) && (t + 1 < tend);
        float4 nx = make_float4(0.f, 0.f, 0.f, 0.f);
        if (ld)                               // prefetch next h0 row
            nx = *(const float4*)(st + (size_t)(t + 1) * H + tid * 4);

        const float* hrow = &hb[cur][36 * ke];
        MV_CORE(hrow);
        if (wr) {
            *(float4*)(st + (size_t)t * H + j0) = make_float4(
                a0 + bias.x, a1 + bias.y, a2 + bias.z, a3 + bias.w);
        }
        if (ld)
            *(float4*)&hb[cur ^ 1][PD(tid * 4)] = nx;
        __syncthreads();
    }
}

// ---------------------------------------------------------------------------
extern "C" void kernel_launch(void* const* d_in, const int* in_sizes, int n_in,
                              void* d_out, int out_size, void* d_ws, size_t ws_size,
                              hipStream_t stream)
{
    (void)in_sizes; (void)n_in; (void)out_size; (void)d_ws; (void)ws_size;
    const float* x  = (const float*)d_in[0];
    const float* h0 = (const float*)d_in[1];
    const float* WI = (const float*)d_in[2];
    const float* BI = (const float*)d_in[3];
    const float* WH = (const float*)d_in[4];
    const float* BH = (const float*)d_in[5];
    float* out = (float*)d_out;

    // 1) pre0 = x @ WI0 + BI0                       -> out
    k_gemm_pre0<<<dim3(1024, 4), 256, 0, stream>>>(x, WI, BI, out);
    // 2) layer-0 recurrence, in-place: out <- h0_t stream; h_final[0]
    k_rec<<<64, 512, 0, stream>>>(WH, BH, h0, out, out + OUT_ELEMS);
    // 3) P = h0 @ WI1 + BI1, in-place: out <- P_t stream
    k_mv1<<<NBATCH * TSEG, 512, 0, stream>>>(WI + H * H, BI + H, out);
    // 4) layer-1 recurrence, in-place: out <- h1_t stream; h_final[1]
    k_rec<<<64, 512, 0, stream>>>(WH + H * H, BH + H, h0 + HSZ, out,
                                  out + OUT_ELEMS + HSZ);
}

// Round 4
// 3513.490 us; speedup vs baseline: 5.4489x; 1.2553x over previous
//
#include <hip/hip_runtime.h>
#include <math.h>

// Problem constants
#define T_STEPS 2048
#define H 256
#define NBATCH 64
#define OUT_ELEMS 33554432   // NBATCH*T_STEPS*H
#define HSZ 16384            // NBATCH*H

// Chunked pre-activation prefetch for the recurrent kernels
#define CH 4
#define NCHUNK (T_STEPS / CH)

// t-segments for the independent-row MV kernel (layer-1 input transform):
// 64 b x 4 segments = 256 wgs = exactly one per CU.
#define TSEG 4
#define TROWS (T_STEPS / TSEG)

// Bank-skewed LDS h row: slice ke (32 floats) starts at 36*ke floats, so the
// 8 slice bases hit banks 0,4,8,...,28 -> each wave ds_read_b128 covers all
// 32 banks exactly once (proven conflict-free in round 3: SQ_LDS_BANK_CONFLICT=0).
#define HP 288
#define PD(k) ((k) + (((k) >> 5) << 2))

typedef float v2f __attribute__((ext_vector_type(2)));

// Workgroup barrier WITHOUT the vmcnt(0) drain __syncthreads would emit.
// Only LDS ordering (lgkmcnt) is needed across the barrier for the h
// double-buffer; global stores stay in flight (fire-and-forget).
#define BAR() asm volatile("s_waitcnt lgkmcnt(0)\n\ts_barrier" ::: "memory")

// 8-lane butterfly reduce on the VALU via DPP (no LDS-pipe traffic).
__device__ __forceinline__ float red8(float v) {
    v += __int_as_float(__builtin_amdgcn_update_dpp(
            0, __float_as_int(v), 0xB1, 0xF, 0xF, true));   // quad_perm(1,0,3,2)
    v += __int_as_float(__builtin_amdgcn_update_dpp(
            0, __float_as_int(v), 0x4E, 0xF, 0xF, true));   // quad_perm(2,3,0,1)
    v += __int_as_float(__builtin_amdgcn_update_dpp(
            0, __float_as_int(v), 0x141, 0xF, 0xF, true));  // row_half_mirror
    return v;
}

// Fast tanh: 1 - 2/(exp(2x)+1). v_exp_f32 + v_rcp_f32, ~2e-7 abs error,
// exact +/-1 at saturation (exp->inf/0), NaN-free for finite x.
__device__ __forceinline__ float ftanh(float x) {
    float e = __expf(2.0f * x);
    return __builtin_fmaf(-2.0f, __builtin_amdgcn_rcpf(e + 1.0f), 1.0f);
}

// ---------------------------------------------------------------------------
// Phase 1: pre0[b][t][n] = x[b][t][:] @ WI0 + BI0   (written into d_out)
// (proven kernel, unchanged)
// ---------------------------------------------------------------------------
__global__ __launch_bounds__(256) void k_gemm_pre0(
    const float* __restrict__ x, const float* __restrict__ WI,
    const float* __restrict__ BI, float* __restrict__ pre)
{
    __shared__ float As[16][132];   // A stored transposed [k][m], padded
    __shared__ float Bs[16][68];
    const int tid = threadIdx.x;
    const size_t mbase = (size_t)blockIdx.x * 128;
    const int nbase = blockIdx.y * 64;
    const int am = tid >> 1, ak = (tid & 1) * 8;
    const int bk = tid >> 4, bn = (tid & 15) * 4;
    const int ty = tid >> 4, tx = tid & 15;
    const int m0 = ty * 8, n0 = tx * 4;
    float acc[8][4];
    #pragma unroll
    for (int i = 0; i < 8; i++)
        #pragma unroll
        for (int j = 0; j < 4; j++) acc[i][j] = 0.f;

    for (int k0 = 0; k0 < 256; k0 += 16) {
        float4 a0 = *(const float4*)(x + (mbase + am) * 256 + k0 + ak);
        float4 a1 = *(const float4*)(x + (mbase + am) * 256 + k0 + ak + 4);
        float4 bv = *(const float4*)(WI + (size_t)(k0 + bk) * 256 + nbase + bn);
        __syncthreads();
        As[ak + 0][am] = a0.x; As[ak + 1][am] = a0.y;
        As[ak + 2][am] = a0.z; As[ak + 3][am] = a0.w;
        As[ak + 4][am] = a1.x; As[ak + 5][am] = a1.y;
        As[ak + 6][am] = a1.z; As[ak + 7][am] = a1.w;
        *(float4*)&Bs[bk][bn] = bv;
        __syncthreads();
        #pragma unroll
        for (int kk = 0; kk < 16; kk++) {
            float4 av0 = *(const float4*)&As[kk][m0];
            float4 av1 = *(const float4*)&As[kk][m0 + 4];
            float4 bv4 = *(const float4*)&Bs[kk][n0];
            float a[8] = {av0.x, av0.y, av0.z, av0.w, av1.x, av1.y, av1.z, av1.w};
            float b[4] = {bv4.x, bv4.y, bv4.z, bv4.w};
            #pragma unroll
            for (int i = 0; i < 8; i++)
                #pragma unroll
                for (int j = 0; j < 4; j++)
                    acc[i][j] += a[i] * b[j];
        }
    }
    float4 bi = *(const float4*)(BI + nbase + n0);
    #pragma unroll
    for (int i = 0; i < 8; i++) {
        float4 r;
        r.x = acc[i][0] + bi.x; r.y = acc[i][1] + bi.y;
        r.z = acc[i][2] + bi.z; r.w = acc[i][3] + bi.w;
        *(float4*)(pre + (mbase + m0 + i) * 256 + nbase + n0) = r;
    }
}

// Register-blocked MV core, packed-f32 (v_pk_fma_f32) version.
// Thread map: ke = tid&7 (32-k slice), jb = tid>>3 (4 output columns).
// Weights repacked as k-pairs: Wp{c}[p] = {W[k0+2p][j0+c], W[k0+2p+1][j0+c]}.
// 64 pk-FMA wave-instrs replace 128 scalar FMAs.
#define MV_CORE(HROW)                                                       \
    float a0, a1, a2, a3;                                                   \
    {                                                                       \
        v2f c0 = {0.f, 0.f}, c1 = {0.f, 0.f};                               \
        v2f c2 = {0.f, 0.f}, c3 = {0.f, 0.f};                               \
        _Pragma("unroll")                                                   \
        for (int q = 0; q < 8; q++) {                                       \
            float4 h4 = *(const float4*)((HROW) + 4 * q);                   \
            v2f hA = {h4.x, h4.y}, hB = {h4.z, h4.w};                       \
            c0 = __builtin_elementwise_fma(hA, Wp0[2*q],   c0);             \
            c1 = __builtin_elementwise_fma(hA, Wp1[2*q],   c1);             \
            c2 = __builtin_elementwise_fma(hA, Wp2[2*q],   c2);             \
            c3 = __builtin_elementwise_fma(hA, Wp3[2*q],   c3);             \
            c0 = __builtin_elementwise_fma(hB, Wp0[2*q+1], c0);             \
            c1 = __builtin_elementwise_fma(hB, Wp1[2*q+1], c1);             \
            c2 = __builtin_elementwise_fma(hB, Wp2[2*q+1], c2);             \
            c3 = __builtin_elementwise_fma(hB, Wp3[2*q+1], c3);             \
        }                                                                   \
        a0 = c0.x + c0.y; a1 = c1.x + c1.y;                                 \
        a2 = c2.x + c2.y; a3 = c3.x + c3.y;                                 \
        a0 = red8(a0); a1 = red8(a1); a2 = red8(a2); a3 = red8(a3);         \
    }

// Load + repack persistent weights (128 VGPRs as 64 v2f pairs).
#define LOAD_WP(WSRC)                                                       \
    v2f Wp0[16], Wp1[16], Wp2[16], Wp3[16];                                 \
    {                                                                       \
        const float* wp = (WSRC) + (size_t)k0 * H + j0;                     \
        _Pragma("unroll")                                                   \
        for (int p = 0; p < 16; p++) {                                      \
            float4 wa = *(const float4*)(wp + (size_t)(2 * p) * H);         \
            float4 wb = *(const float4*)(wp + (size_t)(2 * p + 1) * H);     \
            Wp0[p] = (v2f){wa.x, wb.x};                                     \
            Wp1[p] = (v2f){wa.y, wb.y};                                     \
            Wp2[p] = (v2f){wa.z, wb.z};                                     \
            Wp3[p] = (v2f){wa.w, wb.w};                                     \
        }                                                                   \
    }

// ---------------------------------------------------------------------------
// Recurrent layer: one workgroup per batch row, fully private recurrence.
// h state in skewed LDS double buffer; weights in VGPRs; DPP k-reduce.
// In-place stream: read pre-activation pre_t, write h_t over it.
// Global h stores are batched per chunk and never block a barrier.
// ---------------------------------------------------------------------------
__global__ __launch_bounds__(512, 1) void k_rec(
    const float* __restrict__ W,      // [256][256] recurrent weights
    const float* __restrict__ bias_p, // per-column bias row
    const float* __restrict__ hinit,  // [NBATCH][H] initial hidden (layer slice)
    float* buf,                       // stream base (aliased read/write)
    float* hfin)                      // [NBATCH][H] final hidden out
{
    const int b   = blockIdx.x;
    const int tid = threadIdx.x;
    const int ke  = tid & 7;
    const int jb  = tid >> 3;         // 0..63
    const int j0  = jb * 4;
    const int k0  = ke * 32;
    const bool wr = (ke == 0);

    __shared__ float hb[2][HP];

    LOAD_WP(W);

    float4 bias = make_float4(0.f, 0.f, 0.f, 0.f);
    if (wr) bias = *(const float4*)(bias_p + j0);

    if (tid < 64)
        *(float4*)&hb[0][PD(tid * 4)] = *(const float4*)(hinit + b * H + tid * 4);

    float* st = buf + (size_t)b * T_STEPS * H;

    float4 pc[CH], pn[CH];
    if (wr) {
        #pragma unroll
        for (int s = 0; s < CH; s++)
            pc[s] = *(const float4*)(st + (size_t)s * H + j0);
    }
    __syncthreads();

    for (int n = 0; n < NCHUNK; n++) {
        if (wr && n + 1 < NCHUNK) {          // prefetch next chunk's pre-acts
            #pragma unroll
            for (int s = 0; s < CH; s++)
                pn[s] = *(const float4*)(st + (size_t)((n + 1) * CH + s) * H + j0);
        }
        float4 vout[CH];
        #pragma unroll
        for (int s = 0; s < CH; s++) {
            const int t = n * CH + s;
            const int par = t & 1;
            const float* hrow = &hb[par][36 * ke];   // PD(k0)
            MV_CORE(hrow);
            if (wr) {
                float v0 = ftanh(a0 + pc[s].x + bias.x);
                float v1 = ftanh(a1 + pc[s].y + bias.y);
                float v2 = ftanh(a2 + pc[s].z + bias.z);
                float v3 = ftanh(a3 + pc[s].w + bias.w);
                *(float4*)&hb[par ^ 1][PD(j0)] = make_float4(v0, v1, v2, v3);
                vout[s] = make_float4(v0, v1, v2, v3);
            }
            BAR();   // lgkmcnt only: h visible; global stores stay async
        }
        if (wr) {
            #pragma unroll
            for (int s = 0; s < CH; s++)
                *(float4*)(st + (size_t)(n * CH + s) * H + j0) = vout[s];
            if (n == NCHUNK - 1)
                *(float4*)(hfin + b * H + j0) = vout[CH - 1];
            if (n + 1 < NCHUNK) {
                pc[0] = pn[0]; pc[1] = pn[1]; pc[2] = pn[2]; pc[3] = pn[3];
            }
        }
    }
}

// ---------------------------------------------------------------------------
// Layer-1 input transform: P[b][t][j] = h0[b][t][:] @ WI1 + BI1, in-place.
// Independent rows -> parallel over (b, t-segment); same MV core.
// 256 wgs = one per CU.
// ---------------------------------------------------------------------------
__global__ __launch_bounds__(512, 1) void k_mv1(
    const float* __restrict__ W2,     // WI layer 1
    const float* __restrict__ bias_p, // BI layer 1
    float* buf)
{
    const int b   = blockIdx.x >> 2;  // 64 b x TSEG=4 segments
    const int seg = blockIdx.x & 3;
    const int tid = threadIdx.x;
    const int ke  = tid & 7;
    const int jb  = tid >> 3;
    const int j0  = jb * 4;
    const int k0  = ke * 32;
    const bool wr = (ke == 0);

    __shared__ float hb[2][HP];

    LOAD_WP(W2);

    float4 bias = make_float4(0.f, 0.f, 0.f, 0.f);
    if (wr) bias = *(const float4*)(bias_p + j0);

    float* st = buf + (size_t)b * T_STEPS * H;
    const int t0 = seg * TROWS, tend = t0 + TROWS;

    if (tid < 64)
        *(float4*)&hb[0][PD(tid * 4)] = *(const float4*)(st + (size_t)t0 * H + tid * 4);
    __syncthreads();

    for (int t = t0; t < tend; t++) {
        const int cur = t & 1;
        const bool ld = (tid < 64) && (t + 1 < tend);
        float4 nx = make_float4(0.f, 0.f, 0.f, 0.f);
        if (ld)                               // prefetch next h0 row
            nx = *(const float4*)(st + (size_t)(t + 1) * H + tid * 4);

        const float* hrow = &hb[cur][36 * ke];
        MV_CORE(hrow);
        if (wr) {
            *(float4*)(st + (size_t)t * H + j0) = make_float4(
                a0 + bias.x, a1 + bias.y, a2 + bias.z, a3 + bias.w);
        }
        if (ld)
            *(float4*)&hb[cur ^ 1][PD(tid * 4)] = nx;
        BAR();   // lgkmcnt only: next-row h staged; P stores stay async
    }
}

// ---------------------------------------------------------------------------
extern "C" void kernel_launch(void* const* d_in, const int* in_sizes, int n_in,
                              void* d_out, int out_size, void* d_ws, size_t ws_size,
                              hipStream_t stream)
{
    (void)in_sizes; (void)n_in; (void)out_size; (void)d_ws; (void)ws_size;
    const float* x  = (const float*)d_in[0];
    const float* h0 = (const float*)d_in[1];
    const float* WI = (const float*)d_in[2];
    const float* BI = (const float*)d_in[3];
    const float* WH = (const float*)d_in[4];
    const float* BH = (const float*)d_in[5];
    float* out = (float*)d_out;

    // 1) pre0 = x @ WI0 + BI0                       -> out
    k_gemm_pre0<<<dim3(1024, 4), 256, 0, stream>>>(x, WI, BI, out);
    // 2) layer-0 recurrence, in-place: out <- h0_t stream; h_final[0]
    k_rec<<<64, 512, 0, stream>>>(WH, BH, h0, out, out + OUT_ELEMS);
    // 3) P = h0 @ WI1 + BI1, in-place: out <- P_t stream
    k_mv1<<<NBATCH * TSEG, 512, 0, stream>>>(WI + H * H, BI + H, out);
    // 4) layer-1 recurrence, in-place: out <- h1_t stream; h_final[1]
    k_rec<<<64, 512, 0, stream>>>(WH + H * H, BH + H, h0 + HSZ, out,
                                  out + OUT_ELEMS + HSZ);
}